// Round 1
// 1009.776 us; speedup vs baseline: 1.3683x; 1.3683x over previous
//
#include <hip/hip_runtime.h>
#include <hip/hip_bf16.h>

// SioConvNet on MI355X. Round 3: occupancy. The 2-barrier reg-staged GEMM runs
// ~5500 cyc/K-step at 1 block/CU (pure HBM-latency exposure). LDS=40KB and
// VGPR=104 permit exactly 4 blocks/CU, so split-K deeper everywhere:
//   tok_in: z=8 -> z=32 (1024 blocks, 4/CU)
//   fc/tin: z=4 atomic (64 blocks each), silu moved into scan_p3
//   ffn1:   z=2 atomic (256 blocks), silu moved into ffn2's A-staging (AACT)
//   ffn2:   z=8 atomic (256 blocks), bias+residual pre-added into h
// Split-bf16 (hi+lo, 3-pass MFMA) retained on every GEMM feeding the recurrence
// (za phase sensitivity amplifies bf16 error ~100x). Vocab GEMM single bf16.
// DEPTH=3, DIM=512, DFF=2048, DT=64, VOCAB=32000, B=2, L=512, M=B*L=1024.

#define LDIM 512
#define SEQL 512
#define DT_ 64
#define NC 16
#define CL 32
#define BK 32

typedef short s16x4 __attribute__((ext_vector_type(4)));
typedef short s16x8 __attribute__((ext_vector_type(8)));
typedef float f32x4 __attribute__((ext_vector_type(4)));

__device__ __forceinline__ unsigned short f2bf(float f) {
  unsigned u = __builtin_bit_cast(unsigned, f);
  return (unsigned short)((u + 0x7fffu + ((u >> 16) & 1u)) >> 16);
}
__device__ __forceinline__ float bf2f(unsigned short h) {
  return __builtin_bit_cast(float, (unsigned)h << 16);
}

// C[M,N] = act(A[M,K] @ W[N,K]^T + bias) (+R). A, W row-major, K contiguous.
// ACT: 0=none, 1=silu (post-sum). ATOM: atomicAdd into C (split-K), no bias/act/res.
// SPL: split-bf16 hi/lo 3-pass MFMA (fp32-class precision).
// AACT: 1 = apply silu to A elements while staging (for pre-activation inputs).
template <int BM, int BN, int ACT, bool RES, bool ATOM, bool BIAS, bool SPL, int AACT = 0>
__global__ __launch_bounds__(256) void gemm_bt(
    const float* __restrict__ A, const float* __restrict__ W,
    const float* __restrict__ bias, const float* __restrict__ R,
    float* __restrict__ C, int M, int N, int K, int kc) {
  constexpr int WM = BM / 2, WN = BN / 2, TM = WM / 16, TN = WN / 16;
  constexpr int LDA = BK + 8;  // rows 80B apart -> 16B-aligned, 2-way-bank (free)
  constexpr int PLANES = SPL ? 2 : 1;
  __shared__ __align__(16) short As[BM * LDA * PLANES];
  __shared__ __align__(16) short Bs[BN * LDA * PLANES];

  const int tid = threadIdx.x;
  const int wid = tid >> 6, lane = tid & 63;
  const int q = lane >> 4, l16 = lane & 15;
  const int wm = (wid >> 1) * WM, wn = (wid & 1) * WN;
  const int m0 = blockIdx.y * BM, n0 = blockIdx.x * BN;
  const int kbeg = blockIdx.z * kc;
  const int kend = min(K, kbeg + kc);

  f32x4 acc[TM][TN] = {};

  constexpr int AF = BM * BK / 1024;  // float4 loads per thread for A tile
  constexpr int BF = BN * BK / 1024;

  for (int k0 = kbeg; k0 < kend; k0 += BK) {
#pragma unroll
    for (int t = 0; t < AF; t++) {
      int fi = tid + t * 256;
      int row = fi >> 3, col = (fi & 7) << 2;
      float4 v = *(const float4*)(A + (size_t)(m0 + row) * K + k0 + col);
      float* vp = (float*)&v;
      s16x4 hv, lv;
#pragma unroll
      for (int c = 0; c < 4; c++) {
        if (AACT == 1) vp[c] = vp[c] / (1.f + __expf(-vp[c]));
        unsigned short hb = f2bf(vp[c]);
        hv[c] = (short)hb;
        if (SPL) lv[c] = (short)f2bf(vp[c] - bf2f(hb));
      }
      *(s16x4*)(&As[row * LDA + col]) = hv;
      if (SPL) *(s16x4*)(&As[BM * LDA + row * LDA + col]) = lv;
    }
#pragma unroll
    for (int t = 0; t < BF; t++) {
      int fi = tid + t * 256;
      int row = fi >> 3, col = (fi & 7) << 2;
      float4 v = *(const float4*)(W + (size_t)(n0 + row) * K + k0 + col);
      const float* vp = (const float*)&v;
      s16x4 hv, lv;
#pragma unroll
      for (int c = 0; c < 4; c++) {
        unsigned short hb = f2bf(vp[c]);
        hv[c] = (short)hb;
        if (SPL) lv[c] = (short)f2bf(vp[c] - bf2f(hb));
      }
      *(s16x4*)(&Bs[row * LDA + col]) = hv;
      if (SPL) *(s16x4*)(&Bs[BN * LDA + row * LDA + col]) = lv;
    }
    __syncthreads();
    s16x8 ah[TM], bh[TN], al[TM], bl[TN];
#pragma unroll
    for (int i = 0; i < TM; i++) {
      ah[i] = *(const s16x8*)(&As[(wm + i * 16 + l16) * LDA + q * 8]);
      if (SPL) al[i] = *(const s16x8*)(&As[BM * LDA + (wm + i * 16 + l16) * LDA + q * 8]);
    }
#pragma unroll
    for (int j = 0; j < TN; j++) {
      bh[j] = *(const s16x8*)(&Bs[(wn + j * 16 + l16) * LDA + q * 8]);
      if (SPL) bl[j] = *(const s16x8*)(&Bs[BN * LDA + (wn + j * 16 + l16) * LDA + q * 8]);
    }
#pragma unroll
    for (int i = 0; i < TM; i++)
#pragma unroll
      for (int j = 0; j < TN; j++) {
        acc[i][j] = __builtin_amdgcn_mfma_f32_16x16x32_bf16(ah[i], bh[j], acc[i][j], 0, 0, 0);
        if (SPL) {
          acc[i][j] = __builtin_amdgcn_mfma_f32_16x16x32_bf16(ah[i], bl[j], acc[i][j], 0, 0, 0);
          acc[i][j] = __builtin_amdgcn_mfma_f32_16x16x32_bf16(al[i], bh[j], acc[i][j], 0, 0, 0);
        }
      }
    __syncthreads();
  }

#pragma unroll
  for (int i = 0; i < TM; i++)
#pragma unroll
    for (int j = 0; j < TN; j++)
#pragma unroll
      for (int r = 0; r < 4; r++) {
        int m = m0 + wm + i * 16 + q * 4 + r;
        int n = n0 + wn + j * 16 + l16;
        float v = acc[i][j][r];
        if (BIAS) v += bias[n];
        if (ACT == 1) v = v / (1.f + __expf(-v));
        if (RES) v += R[(size_t)m * N + n];
        if (ATOM) atomicAdd(&C[(size_t)m * N + n], v);
        else C[(size_t)m * N + n] = v;
      }
}

// C[i] = (add ? C[i] : 0) + b[i & mask] — bias broadcast/init for split-K atomics.
__global__ __launch_bounds__(256) void bias_bcast(float* __restrict__ C,
                                                  const float* __restrict__ b,
                                                  int mask, int add) {
  int i = blockIdx.x * 256 + threadIdx.x;
  float v = b[i & mask];
  if (add) v += C[i];
  C[i] = v;
}

// LayerNorm over last dim 512; one wave per row.
__global__ __launch_bounds__(256) void ln512(const float* __restrict__ x,
                                             const float* __restrict__ g,
                                             const float* __restrict__ b,
                                             float* __restrict__ o) {
  int wid = threadIdx.x >> 6, lane = threadIdx.x & 63;
  int row = blockIdx.x * 4 + wid;
  const float* xr = x + (size_t)row * 512 + lane * 8;
  float4 v0 = *(const float4*)xr;
  float4 v1 = *(const float4*)(xr + 4);
  float s = v0.x + v0.y + v0.z + v0.w + v1.x + v1.y + v1.z + v1.w;
  float ss = v0.x * v0.x + v0.y * v0.y + v0.z * v0.z + v0.w * v0.w +
             v1.x * v1.x + v1.y * v1.y + v1.z * v1.z + v1.w * v1.w;
#pragma unroll
  for (int m = 32; m; m >>= 1) { s += __shfl_xor(s, m); ss += __shfl_xor(ss, m); }
  float mean = s * (1.f / 512.f);
  float var = ss * (1.f / 512.f) - mean * mean;
  float rstd = rsqrtf(var + 1e-5f);
  const float* gp = g + lane * 8;
  const float* bp = b + lane * 8;
  float4 g0 = *(const float4*)gp, g1 = *(const float4*)(gp + 4);
  float4 b0 = *(const float4*)bp, b1 = *(const float4*)(bp + 4);
  float* op = o + (size_t)row * 512 + lane * 8;
  float4 r0, r1;
  r0.x = (v0.x - mean) * rstd * g0.x + b0.x;
  r0.y = (v0.y - mean) * rstd * g0.y + b0.y;
  r0.z = (v0.z - mean) * rstd * g0.z + b0.z;
  r0.w = (v0.w - mean) * rstd * g0.w + b0.w;
  r1.x = (v1.x - mean) * rstd * g1.x + b1.x;
  r1.y = (v1.y - mean) * rstd * g1.y + b1.y;
  r1.z = (v1.z - mean) * rstd * g1.z + b1.z;
  r1.w = (v1.w - mean) * rstd * g1.w + b1.w;
  *(float4*)op = r0;
  *(float4*)(op + 4) = r1;
}

// a[b,i,d] from za: a = za * rsqrt(|za|^2) * exp(-|za|^2)
__device__ __forceinline__ float2 a_of(const float* __restrict__ za, int b, int i, int d) {
  float zr = za[(size_t)(b * SEQL + i) * 128 + 2 * d];
  float zi = za[(size_t)(b * SEQL + i) * 128 + 2 * d + 1];
  float m2 = zr * zr + zi * zi;
  float sc = rsqrtf(m2) * __expf(-m2);
  return make_float2(zr * sc, zi * sc);
}

// xsm1[i]: 0 for i==0, h0c for i==1, u[i-2] (real) otherwise.
__device__ __forceinline__ float2 xsm1_of(const float* __restrict__ u,
                                          const float* __restrict__ h0,
                                          int b, int i, int d) {
  if (i == 0) return make_float2(0.f, 0.f);
  if (i == 1) return make_float2(h0[d * 2], h0[d * 2 + 1]);
  return make_float2(u[(size_t)(b * SEQL + i - 2) * DT_ + d], 0.f);
}

// Phase 1: per (b,d,chunk): A = prod a[i], Bv = backward eval with t_end=0.
__global__ __launch_bounds__(256) void scan_p1(const float* __restrict__ za,
                                               const float* __restrict__ u,
                                               const float* __restrict__ h0,
                                               float2* __restrict__ cA,
                                               float2* __restrict__ cB) {
  int tid = blockIdx.x * 256 + threadIdx.x;  // 2048 = B*NC*D, d fastest
  int d = tid & 63, c = (tid >> 6) & (NC - 1), b = tid >> 10;
  float2 Aa = make_float2(1.f, 0.f), Bv = make_float2(0.f, 0.f);
  for (int i = c * CL + CL - 1; i >= c * CL; i--) {
    float2 a = a_of(za, b, i, d);
    float2 xs = xsm1_of(u, h0, b, i, d);
    float2 nb, nA;
    nb.x = xs.x + a.x * Bv.x - a.y * Bv.y;
    nb.y = xs.y + a.x * Bv.y + a.y * Bv.x;
    nA.x = a.x * Aa.x - a.y * Aa.y;
    nA.y = a.x * Aa.y + a.y * Aa.x;
    Bv = nb; Aa = nA;
  }
  cA[tid] = Aa;
  cB[tid] = Bv;
}

// Phase 2: backward combine over the NC chunks, store t at each chunk end.
__global__ __launch_bounds__(128) void scan_p2(const float* __restrict__ u,
                                               const float2* __restrict__ cA,
                                               const float2* __restrict__ cB,
                                               float2* __restrict__ tE) {
  int tid = threadIdx.x;  // 128 = B*D
  int d = tid & 63, b = tid >> 6;
  float2 t = make_float2(u[(size_t)(b * SEQL + SEQL - 2) * DT_ + d], 0.f);  // t[L]=xs[L-1]
  for (int c = NC - 1; c >= 0; c--) {
    int idx = (b << 10) + (c << 6) + d;
    tE[idx] = t;
    float2 A = cA[idx], Bv = cB[idx];
    float2 nt;
    nt.x = A.x * t.x - A.y * t.y + Bv.x;
    nt.y = A.x * t.y + A.y * t.x + Bv.y;
    t = nt;
  }
}

// Phase 3: redo chunk backward scan from known t_end; p = real(h) * silu(y).
// (y arrives PRE-activation now that fc runs as split-K atomic.)
__global__ __launch_bounds__(256) void scan_p3(const float* __restrict__ za,
                                               const float* __restrict__ u,
                                               const float* __restrict__ h0,
                                               const float* __restrict__ y,
                                               const float2* __restrict__ tE,
                                               float* __restrict__ p) {
  int tid = blockIdx.x * 256 + threadIdx.x;
  int d = tid & 63, c = (tid >> 6) & (NC - 1), b = tid >> 10;
  float2 t = tE[tid];
  for (int i = c * CL + CL - 1; i >= c * CL; i--) {
    float2 a = a_of(za, b, i, d);
    float2 xs = xsm1_of(u, h0, b, i, d);
    float2 nt;
    nt.x = xs.x + a.x * t.x - a.y * t.y;
    nt.y = xs.y + a.x * t.y + a.y * t.x;
    t = nt;
    float hr = t.x;
    if (i == SEQL - 1) hr += u[(size_t)(b * SEQL + SEQL - 1) * DT_ + d];
    size_t o = (size_t)(b * SEQL + i) * DT_ + d;
    float yv = y[o];
    yv = yv / (1.f + __expf(-yv));
    p[o] = hr * yv;
  }
}

extern "C" void kernel_launch(void* const* d_in, const int* in_sizes, int n_in,
                              void* d_out, int out_size, void* d_ws, size_t ws_size,
                              hipStream_t stream) {
  const float* x        = (const float*)d_in[0];
  const float* tok_in_w = (const float*)d_in[1];
  const float* tok_in_b = (const float*)d_in[2];
  const float* ln1_g    = (const float*)d_in[3];
  const float* ln1_b    = (const float*)d_in[4];
  const float* fc_w     = (const float*)d_in[5];
  const float* fc_b     = (const float*)d_in[6];
  const float* tin_w    = (const float*)d_in[7];
  const float* tin_b    = (const float*)d_in[8];
  const float* a_w      = (const float*)d_in[9];
  const float* h0       = (const float*)d_in[10];
  const float* tout_w   = (const float*)d_in[11];
  const float* tout_b   = (const float*)d_in[12];
  const float* ln2_g    = (const float*)d_in[13];
  const float* ln2_b    = (const float*)d_in[14];
  const float* ffn_w1   = (const float*)d_in[15];
  const float* ffn_b1   = (const float*)d_in[16];
  const float* ffn_w2   = (const float*)d_in[17];
  const float* ffn_b2   = (const float*)d_in[18];
  const float* lnf_g    = (const float*)d_in[19];
  const float* lnf_b    = (const float*)d_in[20];
  const float* tok_out_w = (const float*)d_in[21];
  const float* tok_out_b = (const float*)d_in[22];
  float* out = (float*)d_out;

  float* ws = (float*)d_ws;
  float* h  = ws;                 // 1024*512
  float* xn = h + 524288;         // 1024*512
  float* y  = xn + 524288;        // 1024*64
  float* u  = y + 65536;          // 1024*64
  float* za = u + 65536;          // 1024*128
  float* p  = za + 131072;        // 1024*64
  float* f1 = p + 65536;          // 1024*2048
  float2* cA = (float2*)(f1 + 2097152);  // 2048
  float2* cB = cA + 2048;
  float2* tE = cB + 2048;

  dim3 blk(256);

  // h = x @ tok_in_w.T + tok_in_b. Split-K=32 (1024 blocks -> 4 blocks/CU,
  // LDS=40KB*4=160KB exact fit; VGPR 104<=128). SPLIT bf16: h feeds the
  // za-phase amplifier — must be fp32-class.
  bias_bcast<<<2048, blk, 0, stream>>>(h, tok_in_b, 511, 0);
  gemm_bt<128, 128, 0, false, true, false, true><<<dim3(4, 8, 32), blk, 0, stream>>>(
      x, tok_in_w, nullptr, nullptr, h, 1024, 512, 32000, 1024);

  for (int l = 0; l < 3; l++) {
    ln512<<<256, blk, 0, stream>>>(h, ln1_g + l * 512, ln1_b + l * 512, xn);
    // fc: y = xn @ fc_w.T + fc_b (pre-act; silu applied in scan_p3). z=4 atomic.
    bias_bcast<<<256, blk, 0, stream>>>(y, fc_b + l * 64, 63, 0);
    gemm_bt<64, 64, 0, false, true, false, true><<<dim3(1, 16, 4), blk, 0, stream>>>(
        xn, fc_w + l * 32768, nullptr, nullptr, y, 1024, 64, 512, 128);
    // tin: u = xn @ tin_w.T + tin_b. z=4 atomic.
    bias_bcast<<<256, blk, 0, stream>>>(u, tin_b + l * 64, 63, 0);
    gemm_bt<64, 64, 0, false, true, false, true><<<dim3(1, 16, 4), blk, 0, stream>>>(
        xn, tin_w + l * 32768, nullptr, nullptr, u, 1024, 64, 512, 128);
    gemm_bt<64, 64, 0, false, false, false, true><<<dim3(2, 16, 1), blk, 0, stream>>>(
        u, a_w + l * 8192, nullptr, nullptr, za, 1024, 128, 64, 64);
    scan_p1<<<8, blk, 0, stream>>>(za, u, h0 + l * 128, cA, cB);
    scan_p2<<<1, 128, 0, stream>>>(u, cA, cB, tE);
    scan_p3<<<8, blk, 0, stream>>>(za, u, h0 + l * 128, y, tE, p);
    gemm_bt<128, 128, 0, true, false, true, true><<<dim3(4, 8, 1), blk, 0, stream>>>(
        p, tout_w + l * 32768, tout_b + l * 512, h, h, 1024, 512, 64, 64);
    ln512<<<256, blk, 0, stream>>>(h, ln2_g + l * 512, ln2_b + l * 512, xn);
    // ffn1: f1 = xn @ w1.T + b1 (pre-act; silu applied during ffn2 A-staging).
    // z=2 atomic -> 256 blocks.
    bias_bcast<<<8192, blk, 0, stream>>>(f1, ffn_b1 + l * 2048, 2047, 0);
    gemm_bt<128, 128, 0, false, true, false, true><<<dim3(16, 8, 2), blk, 0, stream>>>(
        xn, ffn_w1 + l * 1048576, nullptr, nullptr, f1, 1024, 2048, 512, 256);
    // ffn2: h = silu(f1) @ w2.T + b2 + h. Bias+residual pre-merged into h,
    // then z=8 atomic (256 blocks) with silu-on-A-staging.
    bias_bcast<<<2048, blk, 0, stream>>>(h, ffn_b2 + l * 512, 511, 1);
    gemm_bt<128, 128, 0, false, true, false, true, 1><<<dim3(4, 8, 8), blk, 0, stream>>>(
        f1, ffn_w2 + l * 1048576, nullptr, nullptr, h, 1024, 512, 2048, 256);
  }

  ln512<<<256, blk, 0, stream>>>(h, lnf_g, lnf_b, xn);
  gemm_bt<128, 128, 0, false, false, true, false><<<dim3(250, 8, 1), blk, 0, stream>>>(
      xn, tok_out_w, tok_out_b, nullptr, out, 1024, 32000, 512, 512);
}